// Round 15
// baseline (129.028 us; speedup 1.0000x reference)
//
#include <hip/hip_runtime.h>

typedef float v2f __attribute__((ext_vector_type(2)));
typedef float v4f __attribute__((ext_vector_type(4)));

#define HW      1024   // H*W = BN channel count (spatial positions)
#define NROWS   4096   // B*C = reduction size per channel
#define NLAYERS 30
#define TPB     256

// ---------------------------------------------------------------------------
// Packed-f32 VOP3P ops.
// ---------------------------------------------------------------------------
static __device__ __forceinline__ v2f pk_fma(v2f a, v2f b, v2f c) {
    v2f d; asm("v_pk_fma_f32 %0, %1, %2, %3" : "=v"(d) : "v"(a), "v"(b), "v"(c));
    return d;
}
static __device__ __forceinline__ v2f pk_add(v2f a, v2f b) {
    v2f d; asm("v_pk_add_f32 %0, %1, %2" : "=v"(d) : "v"(a), "v"(b));
    return d;
}

// ---------------------------------------------------------------------------
// DPP-based wave64 sum: pure VALU, lane 63 = wave total.
// ---------------------------------------------------------------------------
template <int CTRL, int RMASK>
__device__ __forceinline__ float dpp_add(float x) {
    int t = __builtin_amdgcn_update_dpp(0, __builtin_bit_cast(int, x),
                                        CTRL, RMASK, 0xf, true);
    return x + __builtin_bit_cast(float, t);
}
__device__ __forceinline__ float wave_sum64(float x) {
    x = dpp_add<0x111, 0xf>(x);   // row_shr:1
    x = dpp_add<0x112, 0xf>(x);   // row_shr:2
    x = dpp_add<0x114, 0xf>(x);   // row_shr:4
    x = dpp_add<0x118, 0xf>(x);   // row_shr:8
    x = dpp_add<0x142, 0xa>(x);   // row_bcast15 -> rows 1,3
    x = dpp_add<0x143, 0xc>(x);   // row_bcast31 -> rows 2,3
    return x;                     // lane 63 = wave total
}

// ---------------------------------------------------------------------------
// Generic 64x64-tile transpose (verified R7-R12, unchanged).
// ---------------------------------------------------------------------------
__global__ __launch_bounds__(TPB) void txp64(const float* __restrict__ src,
                                             float* __restrict__ dst,
                                             int M, int N) {
    __shared__ float tile[64][65];
    const int n0 = blockIdx.x * 64;
    const int m0 = blockIdx.y * 64;
    const int tx = threadIdx.x & 63;
    const int ty = threadIdx.x >> 6;    // 0..3
#pragma unroll
    for (int i = 0; i < 16; ++i) {
        const int r = ty + 4 * i;
        tile[r][tx] = src[(size_t)(m0 + r) * N + n0 + tx];
    }
    __syncthreads();
#pragma unroll
    for (int i = 0; i < 16; ++i) {
        const int r = ty + 4 * i;
        dst[(size_t)(n0 + r) * M + m0 + tx] = tile[tx][r];
    }
}

// ---------------------------------------------------------------------------
// Main kernel: 4 waves/channel on transposed ws rows, x1 IN REGISTERS
// (16 elems/thread -> 4 v4f = 16 regs; total ~70 VGPR -> genuinely
// spill-free, unlike the 1-wave designs which silently ran on scratch).
// z-only recurrence (absmax-verified R10-R13):
//   z_{k+1} = om*z_k + dm*x1 + med3(gd*z_k + bd, 0, 6dt),
//     om = 1-dt, dm = m_{k+1} - om*m_k, gd = dt*g, bd = dt*b
//   out = same step with m_30 := 1  (out = y_30 + x1).
// Per-layer LDS = ONE lane63 write + 2 b128 combine reads. Final Euler
// step scatters DIRECTLY to out (T2 deleted): R13 proved L2 merges 16
// same-XCD 4B writes per 64B line at no WRITE_SIZE cost; scattered stores
// are fire-and-forget. XCD swizzle keeps the 16 channels per line together.
// ---------------------------------------------------------------------------
__global__ __launch_bounds__(TPB, 4) void ode_zr4(
    const float* __restrict__ ws, const float* __restrict__ delta_t,
    const float* __restrict__ matrices, const float* __restrict__ gamma,
    const float* __restrict__ beta, float* __restrict__ out) {

    const int bid  = blockIdx.x;
    const int p    = ((bid & 7) << 7) | (bid >> 3);   // XCD-contiguous channel
    const int t    = threadIdx.x;        // 0..255
    const int wid  = t >> 6;             // wave 0..3
    const int lane = t & 63;
    const int c0   = (4 * t) & 255;      // matrix quad base
    const float* row = ws + (size_t)p * NROWS;

    __shared__ __align__(16) v2f red[2][4];   // [parity][wave] = (s,q)

    const float gp = gamma[p];
    const float bp = beta[p];

    v4f xr[4];                           // x1 in registers (16 VGPR)
    v2f z[8];
    v2f s0 = {0.f, 0.f}, s1 = {0.f, 0.f}, q0 = {0.f, 0.f}, q1 = {0.f, 0.f};

    // Coalesced gather (4x dwordx4) + layer 0: z0 = (m0+1)*x1, + stats.
    {
        const v4f m4 = *(const v4f*)(matrices + c0);
        const v2f mA = {m4.x, m4.y}, mB = {m4.z, m4.w};
#pragma unroll
        for (int j = 0; j < 4; ++j) {
            xr[j] = *(const v4f*)(row + 4 * t + 1024 * j);
            const v2f xA = {xr[j].x, xr[j].y}, xB = {xr[j].z, xr[j].w};
            z[2 * j]     = pk_fma(mA, xA, xA);     // m0*x1 + x1
            z[2 * j + 1] = pk_fma(mB, xB, xB);
            s0 = pk_add(s0, z[2 * j]);
            q0 = pk_fma(z[2 * j], z[2 * j], q0);
            s1 = pk_add(s1, z[2 * j + 1]);
            q1 = pk_fma(z[2 * j + 1], z[2 * j + 1], q1);
        }
        const v2f sv = pk_add(s0, s1);
        const v2f qv = pk_add(q0, q1);
        const float ss = wave_sum64(sv.x + sv.y);
        const float qq = wave_sum64(qv.x + qv.y);
        if (lane == 63) red[0][wid] = (v2f){ss, qq};
    }

    v4f   mqc = *(const v4f*)(matrices + c0);          // m_k   (k=0)
    v4f   mqn = *(const v4f*)(matrices + 256 + c0);    // m_{k+1}
    float dtc = delta_t[0];
    float dtn = delta_t[1];
    __syncthreads();

    for (int k = 0; k < NLAYERS - 1; ++k) {
        // Prefetch m_{k+2}/dt_{k+2}; issued a full layer before its barrier.
        const int k2 = (k + 2 < NLAYERS) ? k + 2 : NLAYERS - 1;
        const v4f   mq2   = *(const v4f*)(matrices + k2 * 256 + c0);
        const float dt_nn = delta_t[k2];

        // Combine 4 wave-partials: 2x ds_read_b128 + 6 adds.
        const int par = k & 1;
        const v4f r0 = *(const v4f*)&red[par][0];   // s0,q0,s1,q1
        const v4f r1 = *(const v4f*)&red[par][2];   // s2,q2,s3,q3
        const float S = (r0.x + r0.z) + (r1.x + r1.z);
        const float Q = (r0.y + r0.w) + (r1.y + r1.w);

        const float dtk  = __builtin_amdgcn_fmed3f(dtc, 0.0f, 6.0f);
        const float mean = S * (1.0f / 4096.0f);
        const float var  = fmaf(-mean, mean, Q * (1.0f / 4096.0f));
        const float rstd = rsqrtf(var + 1e-5f);
        const float g    = gp * rstd;                  // gamma folded
        const float b    = fmaf(-mean, g, bp);         // mean folded
        const float om   = 1.0f - dtk;
        const float gd   = g * dtk;                    // dt folded into clamp
        const float bd   = b * dtk;
        const float hi   = 6.0f * dtk;
        const v2f gd2 = {gd, gd}, bd2 = {bd, bd};
        const v2f om2 = {om, om};
        const v2f omn = {-om, -om};
        const v2f mcA = {mqc.x, mqc.y}, mcB = {mqc.z, mqc.w};
        const v2f mnA = {mqn.x, mqn.y}, mnB = {mqn.z, mqn.w};
        const v2f dmA = pk_fma(omn, mcA, mnA);         // m_{k+1} - om*m_k
        const v2f dmB = pk_fma(omn, mcB, mnB);

        s0 = (v2f){0.f, 0.f}; s1 = (v2f){0.f, 0.f};
        q0 = (v2f){0.f, 0.f}; q1 = (v2f){0.f, 0.f};

        // Fused pass: z' = om*z + dm*x1 + med3(gd*z+bd, 0, hi), + stats.
#pragma unroll
        for (int j = 0; j < 4; ++j) {
            const v2f xA = {xr[j].x, xr[j].y}, xB = {xr[j].z, xr[j].w};
            {
                const int e = 2 * j;
                v2f a = pk_fma(z[e], gd2, bd2);
                a.x = __builtin_amdgcn_fmed3f(a.x, 0.0f, hi);
                a.y = __builtin_amdgcn_fmed3f(a.y, 0.0f, hi);
                v2f u = pk_fma(dmA, xA, a);
                z[e] = pk_fma(om2, z[e], u);
                s0 = pk_add(s0, z[e]);
                q0 = pk_fma(z[e], z[e], q0);
            }
            {
                const int e = 2 * j + 1;
                v2f a = pk_fma(z[e], gd2, bd2);
                a.x = __builtin_amdgcn_fmed3f(a.x, 0.0f, hi);
                a.y = __builtin_amdgcn_fmed3f(a.y, 0.0f, hi);
                v2f u = pk_fma(dmB, xB, a);
                z[e] = pk_fma(om2, z[e], u);
                s1 = pk_add(s1, z[e]);
                q1 = pk_fma(z[e], z[e], q1);
            }
        }
        const v2f sv = pk_add(s0, s1);
        const v2f qv = pk_add(q0, q1);
        const float ss = wave_sum64(sv.x + sv.y);
        const float qq = wave_sum64(qv.x + qv.y);
        if (lane == 63) red[par ^ 1][wid] = (v2f){ss, qq};

        mqc = mqn; mqn = mq2; dtc = dtn; dtn = dt_nn;
        __syncthreads();
    }

    // Final layer (k = 29): m_30 := 1 -> out = y_30 + x1, scattered store
    // straight to out (T2 deleted; L2 merges the 16 partial line-writes).
    {
        const v4f r0 = *(const v4f*)&red[(NLAYERS - 1) & 1][0];
        const v4f r1 = *(const v4f*)&red[(NLAYERS - 1) & 1][2];
        const float S = (r0.x + r0.z) + (r1.x + r1.z);
        const float Q = (r0.y + r0.w) + (r1.y + r1.w);

        const float dtk  = __builtin_amdgcn_fmed3f(dtc, 0.0f, 6.0f);
        const float mean = S * (1.0f / 4096.0f);
        const float var  = fmaf(-mean, mean, Q * (1.0f / 4096.0f));
        const float rstd = rsqrtf(var + 1e-5f);
        const float g    = gp * rstd;
        const float b    = fmaf(-mean, g, bp);
        const float om   = 1.0f - dtk;
        const float gd   = g * dtk;
        const float bd   = b * dtk;
        const float hi   = 6.0f * dtk;
        const v2f gd2 = {gd, gd}, bd2 = {bd, bd};
        const v2f om2 = {om, om};
        const v2f omn = {-om, -om};
        const v2f one2 = {1.0f, 1.0f};
        const v2f mcA = {mqc.x, mqc.y}, mcB = {mqc.z, mqc.w};
        const v2f dmA = pk_fma(omn, mcA, one2);   // 1 - om*m_29
        const v2f dmB = pk_fma(omn, mcB, one2);

        float* op = out + (size_t)(4 * t) * HW + p;   // element e=4t row base
#pragma unroll
        for (int j = 0; j < 4; ++j) {
            const v2f xA = {xr[j].x, xr[j].y}, xB = {xr[j].z, xr[j].w};
            v2f o0, o1;
            {
                v2f a = pk_fma(z[2 * j], gd2, bd2);
                a.x = __builtin_amdgcn_fmed3f(a.x, 0.0f, hi);
                a.y = __builtin_amdgcn_fmed3f(a.y, 0.0f, hi);
                v2f u = pk_fma(dmA, xA, a);
                o0 = pk_fma(om2, z[2 * j], u);
            }
            {
                v2f a = pk_fma(z[2 * j + 1], gd2, bd2);
                a.x = __builtin_amdgcn_fmed3f(a.x, 0.0f, hi);
                a.y = __builtin_amdgcn_fmed3f(a.y, 0.0f, hi);
                v2f u = pk_fma(dmB, xB, a);
                o1 = pk_fma(om2, z[2 * j + 1], u);
            }
            const size_t base = (size_t)(1024 * j) * HW;   // e = 4t + 1024j + i
            op[base]                  = o0.x;
            op[base + HW]             = o0.y;
            op[base + 2 * (size_t)HW] = o1.x;
            op[base + 3 * (size_t)HW] = o1.y;
        }
    }
}

// ---------------------------------------------------------------------------
// Fallback (proven 55.6 us, round 0): used only if workspace is too small.
// ---------------------------------------------------------------------------
__global__ __launch_bounds__(TPB) void ode_fused(const float* __restrict__ x,
                                                 const float* __restrict__ delta_t,
                                                 const float* __restrict__ matrices,
                                                 const float* __restrict__ gamma,
                                                 const float* __restrict__ beta,
                                                 float* __restrict__ out) {
    const int bid = blockIdx.x;
    const int p   = ((bid & 7) << 7) | (bid >> 3);
    const int t   = threadIdx.x;

    __shared__ float smat[(NLAYERS + 1) * 256];
    __shared__ float sdt[NLAYERS];
    __shared__ __align__(16) v2f red[2][4];

#pragma unroll
    for (int i = 0; i < NLAYERS; ++i)
        smat[i * 256 + t] = matrices[i * 256 + t];
    if (t < NLAYERS)
        sdt[t] = __builtin_amdgcn_fmed3f(delta_t[t], 0.0f, 6.0f);

    v2f x1[8], y[8];
#pragma unroll
    for (int k = 0; k < 8; ++k) {
        x1[k].x = x[(size_t)(t + 512 * k) * HW + p];
        x1[k].y = x[(size_t)(t + 512 * k + 256) * HW + p];
        y[k] = x1[k];
    }

    const float gp   = gamma[p];
    const float bp   = beta[p];
    const int   wid  = t >> 6;
    const int   lane = t & 63;

    __syncthreads();
    float m_cur = smat[t];

    for (int l = 0; l < NLAYERS; ++l) {
        const float dtl = sdt[l];
        const v2f m2    = {m_cur, m_cur};
        const v2f dt2   = {dtl, dtl};
        const v2f om2   = {1.0f - dtl, 1.0f - dtl};

        v2f z[8];
        v2f sA = {0.f, 0.f}, sB = {0.f, 0.f};
        v2f qA = {0.f, 0.f}, qB = {0.f, 0.f};
#pragma unroll
        for (int k = 0; k < 8; k += 2) {
            z[k]     = __builtin_elementwise_fma(m2, x1[k], y[k]);
            z[k + 1] = __builtin_elementwise_fma(m2, x1[k + 1], y[k + 1]);
            sA += z[k];
            sB += z[k + 1];
            qA = __builtin_elementwise_fma(z[k], z[k], qA);
            qB = __builtin_elementwise_fma(z[k + 1], z[k + 1], qB);
        }
#pragma unroll
        for (int k = 0; k < 8; ++k) y[k] *= om2;

        const v2f sv = sA + sB;
        const v2f qv = qA + qB;
        float s = wave_sum64(sv.x + sv.y);
        float q = wave_sum64(qv.x + qv.y);

        const int par = l & 1;
        if (lane == 63) { v2f w; w.x = s; w.y = q; red[par][wid] = w; }
        m_cur = smat[(l + 1) * 256 + t];
        __syncthreads();

        const float4 r0 = *(const float4*)&red[par][0];
        const float4 r1 = *(const float4*)&red[par][2];
        const float S  = (r0.x + r0.z) + (r1.x + r1.z);
        const float S2 = (r0.y + r0.w) + (r1.y + r1.w);

        const float mean = S * (1.0f / 4096.0f);
        const float var  = fmaf(-mean, mean, S2 * (1.0f / 4096.0f));
        const float rstd = rsqrtf(var + 1e-5f);
        const float g    = gp * rstd;
        const float bb   = fmaf(-mean, g, bp);
        const v2f g2 = {g, g}, b2 = {bb, bb};
        const v2f z0 = {0.f, 0.f}, s6 = {6.f, 6.f};
#pragma unroll
        for (int k = 0; k < 8; ++k) {
            v2f a = __builtin_elementwise_fma(z[k], g2, b2);
            a = __builtin_elementwise_max(a, z0);
            a = __builtin_elementwise_min(a, s6);
            y[k] = __builtin_elementwise_fma(dt2, a, y[k]);
        }
    }

#pragma unroll
    for (int k = 0; k < 8; ++k) {
        out[(size_t)(t + 512 * k) * HW + p]       = y[k].x + x1[k].x;
        out[(size_t)(t + 512 * k + 256) * HW + p] = y[k].y + x1[k].y;
    }
}

extern "C" void kernel_launch(void* const* d_in, const int* in_sizes, int n_in,
                              void* d_out, int out_size, void* d_ws, size_t ws_size,
                              hipStream_t stream) {
    const float* x        = (const float*)d_in[0];   // [16,256,32,32]
    const float* delta_t  = (const float*)d_in[1];   // [30,1]
    const float* matrices = (const float*)d_in[2];   // [30,1,1,16,16]
    const float* gamma    = (const float*)d_in[3];   // [1024]
    const float* beta     = (const float*)d_in[4];   // [1024]
    float* out = (float*)d_out;

    const size_t need = (size_t)HW * NROWS * sizeof(float);   // 16 MiB
    if (d_ws != nullptr && ws_size >= need) {
        float* ws = (float*)d_ws;
        // T1: x [4096,1024] -> ws = x^T [1024,4096]
        txp64<<<dim3(HW / 64, NROWS / 64), dim3(TPB), 0, stream>>>(x, ws, NROWS, HW);
        // Main: 4 waves/channel, x1 in registers, scatter direct to out.
        ode_zr4<<<dim3(HW), dim3(TPB), 0, stream>>>(ws, delta_t, matrices, gamma, beta, out);
        // (T2 deleted)
    } else {
        ode_fused<<<dim3(HW), dim3(TPB), 0, stream>>>(x, delta_t, matrices, gamma, beta, out);
    }
}

// Round 16
// 121.670 us; speedup vs baseline: 1.0605x; 1.0605x over previous
//
#include <hip/hip_runtime.h>

typedef float v2f __attribute__((ext_vector_type(2)));
typedef float v4f __attribute__((ext_vector_type(4)));

#define HW      1024   // H*W = BN channel count (spatial positions)
#define NROWS   4096   // B*C = reduction size per channel
#define NLAYERS 30
#define TPB     256

// ---------------------------------------------------------------------------
// Packed-f32 VOP3P ops (asm outputs also pin results into registers).
// ---------------------------------------------------------------------------
static __device__ __forceinline__ v2f pk_fma(v2f a, v2f b, v2f c) {
    v2f d; asm("v_pk_fma_f32 %0, %1, %2, %3" : "=v"(d) : "v"(a), "v"(b), "v"(c));
    return d;
}
static __device__ __forceinline__ v2f pk_add(v2f a, v2f b) {
    v2f d; asm("v_pk_add_f32 %0, %1, %2" : "=v"(d) : "v"(a), "v"(b));
    return d;
}

// ---------------------------------------------------------------------------
// DPP-based wave64 sum: pure VALU, lane 63 = wave total.
// ---------------------------------------------------------------------------
template <int CTRL, int RMASK>
__device__ __forceinline__ float dpp_add(float x) {
    int t = __builtin_amdgcn_update_dpp(0, __builtin_bit_cast(int, x),
                                        CTRL, RMASK, 0xf, true);
    return x + __builtin_bit_cast(float, t);
}
__device__ __forceinline__ float wave_sum64(float x) {
    x = dpp_add<0x111, 0xf>(x);   // row_shr:1
    x = dpp_add<0x112, 0xf>(x);   // row_shr:2
    x = dpp_add<0x114, 0xf>(x);   // row_shr:4
    x = dpp_add<0x118, 0xf>(x);   // row_shr:8
    x = dpp_add<0x142, 0xa>(x);   // row_bcast15 -> rows 1,3
    x = dpp_add<0x143, 0xc>(x);   // row_bcast31 -> rows 2,3
    return x;                     // lane 63 = wave total
}
__device__ __forceinline__ float bcast63(float x) {
    return __builtin_bit_cast(float,
        __builtin_amdgcn_readlane(__builtin_bit_cast(int, x), 63));
}

// ---------------------------------------------------------------------------
// Generic 64x64-tile transpose (verified R7-R15, unchanged).
// ---------------------------------------------------------------------------
__global__ __launch_bounds__(TPB) void txp64(const float* __restrict__ src,
                                             float* __restrict__ dst,
                                             int M, int N) {
    __shared__ float tile[64][65];
    const int n0 = blockIdx.x * 64;
    const int m0 = blockIdx.y * 64;
    const int tx = threadIdx.x & 63;
    const int ty = threadIdx.x >> 6;    // 0..3
#pragma unroll
    for (int i = 0; i < 16; ++i) {
        const int r = ty + 4 * i;
        tile[r][tx] = src[(size_t)(m0 + r) * N + n0 + tx];
    }
    __syncthreads();
#pragma unroll
    for (int i = 0; i < 16; ++i) {
        const int r = ty + 4 * i;
        dst[(size_t)(n0 + r) * M + m0 + tx] = tile[tx][r];
    }
}

// ---------------------------------------------------------------------------
// Main kernel (R12's proven ~35us structure, epilogue changed only):
// 1 wave per channel, barrier-free, z-only recurrence, coalesced gather
// from the transposed ws row, scattered store DIRECT to out (T2 deleted —
// R13 measured WRITE_SIZE stays exactly 16 MB: the 16 same-XCD blocks
// sharing each 64B out-line merge in L2; stores are fire-and-forget).
// p is XCD-swizzled so those 16 channels sit on one XCD (read-neutral:
// each block reads its own ws row regardless of bid->p mapping).
//   z_{k+1} = om*z_k + dm*x1 + med3(gd*z_k + bd, 0, 6dt),
//     om = 1-dt, dm = m_{k+1} - om*m_k, gd = dt*g, bd = dt*b
//   out = same step with m_30 := 1  (out = y_30 + x1).
// ---------------------------------------------------------------------------
__global__ __launch_bounds__(64, 1) void ode_zreg(
    const float* __restrict__ ws, const float* __restrict__ delta_t,
    const float* __restrict__ matrices, const float* __restrict__ gamma,
    const float* __restrict__ beta, float* __restrict__ out) {

    const int bid  = blockIdx.x;
    const int p    = ((bid & 7) << 7) | (bid >> 3);   // XCD-contiguous channel
    const int lane = threadIdx.x;          // 0..63
    const int c0   = 4 * lane;             // matrix quad base (0..252)
    const float* row = ws + (size_t)p * NROWS;

    const float gp = gamma[p];
    const float bp = beta[p];

    v4f xr[16];                            // x1, register-resident (pinned)
    v2f z[32];
    v2f s0 = {0.f, 0.f}, s1 = {0.f, 0.f}, q0 = {0.f, 0.f}, q1 = {0.f, 0.f};

    // Coalesced gather (16x dwordx4) + layer 0: z0 = (m0+1)*x1, + stats.
    {
        const v4f m4 = *(const v4f*)(matrices + c0);
        const v2f mA = {m4.x, m4.y}, mB = {m4.z, m4.w};
#pragma unroll
        for (int j = 0; j < 16; ++j) {
            xr[j] = *(const v4f*)(row + 4 * lane + 256 * j);
            const v2f xA = {xr[j].x, xr[j].y}, xB = {xr[j].z, xr[j].w};
            z[2 * j]     = pk_fma(mA, xA, xA);     // m0*x1 + x1
            z[2 * j + 1] = pk_fma(mB, xB, xB);
            s0 = pk_add(s0, z[2 * j]);
            q0 = pk_fma(z[2 * j], z[2 * j], q0);
            s1 = pk_add(s1, z[2 * j + 1]);
            q1 = pk_fma(z[2 * j + 1], z[2 * j + 1], q1);
        }
    }

    v4f   mqc = *(const v4f*)(matrices + c0);          // m_k   (k=0)
    v4f   mqn = *(const v4f*)(matrices + 256 + c0);    // m_{k+1}
    float dtc = delta_t[0];
    float dtn = delta_t[1];

    for (int k = 0; k < NLAYERS - 1; ++k) {
        // Pin x1 registers: forbids remat-as-reload inside the loop.
        asm volatile("" : "+v"(xr[0]), "+v"(xr[1]), "+v"(xr[2]), "+v"(xr[3]));
        asm volatile("" : "+v"(xr[4]), "+v"(xr[5]), "+v"(xr[6]), "+v"(xr[7]));
        asm volatile("" : "+v"(xr[8]), "+v"(xr[9]), "+v"(xr[10]), "+v"(xr[11]));
        asm volatile("" : "+v"(xr[12]), "+v"(xr[13]), "+v"(xr[14]), "+v"(xr[15]));

        // Prefetch m_{k+2}/dt_{k+2}: ~2 layers of cover, no barrier to
        // drain vmcnt -> latency fully hidden.
        const int k2 = (k + 2 < NLAYERS) ? k + 2 : NLAYERS - 1;
        const v4f   mq2   = *(const v4f*)(matrices + k2 * 256 + c0);
        const float dt_nn = delta_t[k2];

        // In-wave stats of z_k.
        const v2f sv = pk_add(s0, s1);
        const v2f qv = pk_add(q0, q1);
        const float S = bcast63(wave_sum64(sv.x + sv.y));
        const float Q = bcast63(wave_sum64(qv.x + qv.y));

        const float dtk  = __builtin_amdgcn_fmed3f(dtc, 0.0f, 6.0f);
        const float mean = S * (1.0f / 4096.0f);
        const float var  = fmaf(-mean, mean, Q * (1.0f / 4096.0f));
        const float rstd = rsqrtf(var + 1e-5f);
        const float g    = gp * rstd;                  // gamma folded
        const float b    = fmaf(-mean, g, bp);         // mean folded
        const float om   = 1.0f - dtk;
        const float gd   = g * dtk;                    // dt folded into clamp
        const float bd   = b * dtk;
        const float hi   = 6.0f * dtk;
        const v2f gd2 = {gd, gd}, bd2 = {bd, bd};
        const v2f om2 = {om, om};
        const v2f omn = {-om, -om};
        const v2f mcA = {mqc.x, mqc.y}, mcB = {mqc.z, mqc.w};
        const v2f mnA = {mqn.x, mqn.y}, mnB = {mqn.z, mqn.w};
        const v2f dmA = pk_fma(omn, mcA, mnA);         // m_{k+1} - om*m_k
        const v2f dmB = pk_fma(omn, mcB, mnB);

        s0 = (v2f){0.f, 0.f}; s1 = (v2f){0.f, 0.f};
        q0 = (v2f){0.f, 0.f}; q1 = (v2f){0.f, 0.f};

        // Fused pass: z' = om*z + dm*x1 + med3(gd*z+bd, 0, hi), + stats.
#pragma unroll
        for (int j = 0; j < 16; ++j) {
            const v2f xA = {xr[j].x, xr[j].y}, xB = {xr[j].z, xr[j].w};
            {
                const int e = 2 * j;
                v2f a = pk_fma(z[e], gd2, bd2);
                a.x = __builtin_amdgcn_fmed3f(a.x, 0.0f, hi);
                a.y = __builtin_amdgcn_fmed3f(a.y, 0.0f, hi);
                v2f u = pk_fma(dmA, xA, a);
                z[e] = pk_fma(om2, z[e], u);
                s0 = pk_add(s0, z[e]);
                q0 = pk_fma(z[e], z[e], q0);
            }
            {
                const int e = 2 * j + 1;
                v2f a = pk_fma(z[e], gd2, bd2);
                a.x = __builtin_amdgcn_fmed3f(a.x, 0.0f, hi);
                a.y = __builtin_amdgcn_fmed3f(a.y, 0.0f, hi);
                v2f u = pk_fma(dmB, xB, a);
                z[e] = pk_fma(om2, z[e], u);
                s1 = pk_add(s1, z[e]);
                q1 = pk_fma(z[e], z[e], q1);
            }
        }

        mqc = mqn; mqn = mq2; dtc = dtn; dtn = dt_nn;
    }

    // Final layer (k = 29): same step with m_30 := 1 -> out = y_30 + x1,
    // scattered DIRECT to out in the original layout (T2 deleted).
    {
        const v2f sv = pk_add(s0, s1);
        const v2f qv = pk_add(q0, q1);
        const float S = bcast63(wave_sum64(sv.x + sv.y));
        const float Q = bcast63(wave_sum64(qv.x + qv.y));

        const float dtk  = __builtin_amdgcn_fmed3f(dtc, 0.0f, 6.0f);
        const float mean = S * (1.0f / 4096.0f);
        const float var  = fmaf(-mean, mean, Q * (1.0f / 4096.0f));
        const float rstd = rsqrtf(var + 1e-5f);
        const float g    = gp * rstd;
        const float b    = fmaf(-mean, g, bp);
        const float om   = 1.0f - dtk;
        const float gd   = g * dtk;
        const float bd   = b * dtk;
        const float hi   = 6.0f * dtk;
        const v2f gd2 = {gd, gd}, bd2 = {bd, bd};
        const v2f om2 = {om, om};
        const v2f omn = {-om, -om};
        const v2f one2 = {1.0f, 1.0f};
        const v2f mcA = {mqc.x, mqc.y}, mcB = {mqc.z, mqc.w};
        const v2f dmA = pk_fma(omn, mcA, one2);   // 1 - om*m_29
        const v2f dmB = pk_fma(omn, mcB, one2);

        float* op = out + (size_t)(4 * lane) * HW + p;   // elem e=4*lane base
#pragma unroll
        for (int j = 0; j < 16; ++j) {
            const v2f xA = {xr[j].x, xr[j].y}, xB = {xr[j].z, xr[j].w};
            v2f o0, o1;
            {
                v2f a = pk_fma(z[2 * j], gd2, bd2);
                a.x = __builtin_amdgcn_fmed3f(a.x, 0.0f, hi);
                a.y = __builtin_amdgcn_fmed3f(a.y, 0.0f, hi);
                v2f u = pk_fma(dmA, xA, a);
                o0 = pk_fma(om2, z[2 * j], u);
            }
            {
                v2f a = pk_fma(z[2 * j + 1], gd2, bd2);
                a.x = __builtin_amdgcn_fmed3f(a.x, 0.0f, hi);
                a.y = __builtin_amdgcn_fmed3f(a.y, 0.0f, hi);
                v2f u = pk_fma(dmB, xB, a);
                o1 = pk_fma(om2, z[2 * j + 1], u);
            }
            // e = 4*lane + 256*j + i  ->  out[e*HW + p]
            const size_t base = (size_t)(256 * j) * HW;
            op[base]                  = o0.x;
            op[base + HW]             = o0.y;
            op[base + 2 * (size_t)HW] = o1.x;
            op[base + 3 * (size_t)HW] = o1.y;
        }
    }
}

// ---------------------------------------------------------------------------
// Fallback (proven 55.6 us, round 0): used only if workspace is too small.
// ---------------------------------------------------------------------------
__global__ __launch_bounds__(TPB) void ode_fused(const float* __restrict__ x,
                                                 const float* __restrict__ delta_t,
                                                 const float* __restrict__ matrices,
                                                 const float* __restrict__ gamma,
                                                 const float* __restrict__ beta,
                                                 float* __restrict__ out) {
    const int bid = blockIdx.x;
    const int p   = ((bid & 7) << 7) | (bid >> 3);
    const int t   = threadIdx.x;

    __shared__ float smat[(NLAYERS + 1) * 256];
    __shared__ float sdt[NLAYERS];
    __shared__ __align__(16) v2f red[2][4];

#pragma unroll
    for (int i = 0; i < NLAYERS; ++i)
        smat[i * 256 + t] = matrices[i * 256 + t];
    if (t < NLAYERS)
        sdt[t] = __builtin_amdgcn_fmed3f(delta_t[t], 0.0f, 6.0f);

    v2f x1[8], y[8];
#pragma unroll
    for (int k = 0; k < 8; ++k) {
        x1[k].x = x[(size_t)(t + 512 * k) * HW + p];
        x1[k].y = x[(size_t)(t + 512 * k + 256) * HW + p];
        y[k] = x1[k];
    }

    const float gp   = gamma[p];
    const float bp   = beta[p];
    const int   wid  = t >> 6;
    const int   lane = t & 63;

    __syncthreads();
    float m_cur = smat[t];

    for (int l = 0; l < NLAYERS; ++l) {
        const float dtl = sdt[l];
        const v2f m2    = {m_cur, m_cur};
        const v2f dt2   = {dtl, dtl};
        const v2f om2   = {1.0f - dtl, 1.0f - dtl};

        v2f z[8];
        v2f sA = {0.f, 0.f}, sB = {0.f, 0.f};
        v2f qA = {0.f, 0.f}, qB = {0.f, 0.f};
#pragma unroll
        for (int k = 0; k < 8; k += 2) {
            z[k]     = __builtin_elementwise_fma(m2, x1[k], y[k]);
            z[k + 1] = __builtin_elementwise_fma(m2, x1[k + 1], y[k + 1]);
            sA += z[k];
            sB += z[k + 1];
            qA = __builtin_elementwise_fma(z[k], z[k], qA);
            qB = __builtin_elementwise_fma(z[k + 1], z[k + 1], qB);
        }
#pragma unroll
        for (int k = 0; k < 8; ++k) y[k] *= om2;

        const v2f sv = sA + sB;
        const v2f qv = qA + qB;
        float s = wave_sum64(sv.x + sv.y);
        float q = wave_sum64(qv.x + qv.y);

        const int par = l & 1;
        if (lane == 63) { v2f w; w.x = s; w.y = q; red[par][wid] = w; }
        m_cur = smat[(l + 1) * 256 + t];
        __syncthreads();

        const float4 r0 = *(const float4*)&red[par][0];
        const float4 r1 = *(const float4*)&red[par][2];
        const float S  = (r0.x + r0.z) + (r1.x + r1.z);
        const float S2 = (r0.y + r0.w) + (r1.y + r1.w);

        const float mean = S * (1.0f / 4096.0f);
        const float var  = fmaf(-mean, mean, S2 * (1.0f / 4096.0f));
        const float rstd = rsqrtf(var + 1e-5f);
        const float g    = gp * rstd;
        const float bb   = fmaf(-mean, g, bp);
        const v2f g2 = {g, g}, b2 = {bb, bb};
        const v2f z0 = {0.f, 0.f}, s6 = {6.f, 6.f};
#pragma unroll
        for (int k = 0; k < 8; ++k) {
            v2f a = __builtin_elementwise_fma(z[k], g2, b2);
            a = __builtin_elementwise_max(a, z0);
            a = __builtin_elementwise_min(a, s6);
            y[k] = __builtin_elementwise_fma(dt2, a, y[k]);
        }
    }

#pragma unroll
    for (int k = 0; k < 8; ++k) {
        out[(size_t)(t + 512 * k) * HW + p]       = y[k].x + x1[k].x;
        out[(size_t)(t + 512 * k + 256) * HW + p] = y[k].y + x1[k].y;
    }
}

extern "C" void kernel_launch(void* const* d_in, const int* in_sizes, int n_in,
                              void* d_out, int out_size, void* d_ws, size_t ws_size,
                              hipStream_t stream) {
    const float* x        = (const float*)d_in[0];   // [16,256,32,32]
    const float* delta_t  = (const float*)d_in[1];   // [30,1]
    const float* matrices = (const float*)d_in[2];   // [30,1,1,16,16]
    const float* gamma    = (const float*)d_in[3];   // [1024]
    const float* beta     = (const float*)d_in[4];   // [1024]
    float* out = (float*)d_out;

    const size_t need = (size_t)HW * NROWS * sizeof(float);   // 16 MiB
    if (d_ws != nullptr && ws_size >= need) {
        float* ws = (float*)d_ws;
        // T1: x [4096,1024] -> ws = x^T [1024,4096]
        txp64<<<dim3(HW / 64, NROWS / 64), dim3(TPB), 0, stream>>>(x, ws, NROWS, HW);
        // Main: 1-wave/channel barrier-free, scatter direct to out (no T2).
        ode_zreg<<<dim3(HW), dim3(64), 0, stream>>>(ws, delta_t, matrices, gamma, beta, out);
    } else {
        ode_fused<<<dim3(HW), dim3(TPB), 0, stream>>>(x, delta_t, matrices, gamma, beta, out);
    }
}

// Round 17
// 110.151 us; speedup vs baseline: 1.1714x; 1.1046x over previous
//
#include <hip/hip_runtime.h>

typedef float v2f __attribute__((ext_vector_type(2)));
typedef float v4f __attribute__((ext_vector_type(4)));

#define HW      1024   // H*W = BN channel count (spatial positions)
#define NROWS   4096   // B*C = reduction size per channel
#define NLAYERS 30
#define TPB     256

// ---------------------------------------------------------------------------
// Packed-f32 VOP3P ops (asm outputs also pin results into registers).
// ---------------------------------------------------------------------------
static __device__ __forceinline__ v2f pk_fma(v2f a, v2f b, v2f c) {
    v2f d; asm("v_pk_fma_f32 %0, %1, %2, %3" : "=v"(d) : "v"(a), "v"(b), "v"(c));
    return d;
}
static __device__ __forceinline__ v2f pk_add(v2f a, v2f b) {
    v2f d; asm("v_pk_add_f32 %0, %1, %2" : "=v"(d) : "v"(a), "v"(b));
    return d;
}

// ---------------------------------------------------------------------------
// DPP-based wave64 sum: pure VALU, lane 63 = wave total.
// ---------------------------------------------------------------------------
template <int CTRL, int RMASK>
__device__ __forceinline__ float dpp_add(float x) {
    int t = __builtin_amdgcn_update_dpp(0, __builtin_bit_cast(int, x),
                                        CTRL, RMASK, 0xf, true);
    return x + __builtin_bit_cast(float, t);
}
__device__ __forceinline__ float wave_sum64(float x) {
    x = dpp_add<0x111, 0xf>(x);   // row_shr:1
    x = dpp_add<0x112, 0xf>(x);   // row_shr:2
    x = dpp_add<0x114, 0xf>(x);   // row_shr:4
    x = dpp_add<0x118, 0xf>(x);   // row_shr:8
    x = dpp_add<0x142, 0xa>(x);   // row_bcast15 -> rows 1,3
    x = dpp_add<0x143, 0xc>(x);   // row_bcast31 -> rows 2,3
    return x;                     // lane 63 = wave total
}
__device__ __forceinline__ float bcast63(float x) {
    return __builtin_bit_cast(float,
        __builtin_amdgcn_readlane(__builtin_bit_cast(int, x), 63));
}

// ---------------------------------------------------------------------------
// Generic 64x64-tile transpose (verified R7-R16, unchanged).
// ---------------------------------------------------------------------------
__global__ __launch_bounds__(TPB) void txp64(const float* __restrict__ src,
                                             float* __restrict__ dst,
                                             int M, int N) {
    __shared__ float tile[64][65];
    const int n0 = blockIdx.x * 64;
    const int m0 = blockIdx.y * 64;
    const int tx = threadIdx.x & 63;
    const int ty = threadIdx.x >> 6;    // 0..3
#pragma unroll
    for (int i = 0; i < 16; ++i) {
        const int r = ty + 4 * i;
        tile[r][tx] = src[(size_t)(m0 + r) * N + n0 + tx];
    }
    __syncthreads();
#pragma unroll
    for (int i = 0; i < 16; ++i) {
        const int r = ty + 4 * i;
        dst[(size_t)(n0 + r) * M + m0 + tx] = tile[tx][r];
    }
}

// ---------------------------------------------------------------------------
// Main kernel — EXACT R12 structure (measured session-best headline 111.5):
// 1 wave per channel row of ws, barrier-free, z-only recurrence, coalesced
// gather AND coalesced in-place store to ws (T2 does the relayout; R16
// proved scattered stores at 1 wave/SIMD cost ~10-15us of TA time).
// SINGLE CHANGE vs R12: amdgpu_waves_per_eu(1,1). launch_bounds' 2nd arg
// only sets MIN waves/EU; the allocator still caps the register grant for
// potential multi-wave occupancy (measured VGPR=84-112 vs ~170 needed ->
// silent z-spill/remat, the diagnosed ~20us excess in this kernel).
// Pinning max waves/EU = 1 removes that incentive: full 512-reg budget.
//   z_{k+1} = om*z_k + dm*x1 + med3(gd*z_k + bd, 0, 6dt),
//     om = 1-dt, dm = m_{k+1} - om*m_k, gd = dt*g, bd = dt*b
//   out = same step with m_30 := 1  (out = y_30 + x1).
// ---------------------------------------------------------------------------
__global__ __attribute__((amdgpu_waves_per_eu(1, 1)))
__launch_bounds__(64) void ode_zreg(
    float* __restrict__ ws, const float* __restrict__ delta_t,
    const float* __restrict__ matrices, const float* __restrict__ gamma,
    const float* __restrict__ beta) {

    const int p    = blockIdx.x;
    const int lane = threadIdx.x;          // 0..63
    const int c0   = 4 * lane;             // matrix quad base (0..252)
    float* row = ws + (size_t)p * NROWS;

    const float gp = gamma[p];
    const float bp = beta[p];

    v4f xr[16];                            // x1, register-resident (pinned)
    v2f z[32];
    v2f s0 = {0.f, 0.f}, s1 = {0.f, 0.f}, q0 = {0.f, 0.f}, q1 = {0.f, 0.f};

    // Coalesced gather (16x dwordx4) + layer 0: z0 = (m0+1)*x1, + stats.
    {
        const v4f m4 = *(const v4f*)(matrices + c0);
        const v2f mA = {m4.x, m4.y}, mB = {m4.z, m4.w};
#pragma unroll
        for (int j = 0; j < 16; ++j) {
            xr[j] = *(const v4f*)(row + 4 * lane + 256 * j);
            const v2f xA = {xr[j].x, xr[j].y}, xB = {xr[j].z, xr[j].w};
            z[2 * j]     = pk_fma(mA, xA, xA);     // m0*x1 + x1
            z[2 * j + 1] = pk_fma(mB, xB, xB);
            s0 = pk_add(s0, z[2 * j]);
            q0 = pk_fma(z[2 * j], z[2 * j], q0);
            s1 = pk_add(s1, z[2 * j + 1]);
            q1 = pk_fma(z[2 * j + 1], z[2 * j + 1], q1);
        }
    }

    v4f   mqc = *(const v4f*)(matrices + c0);          // m_k   (k=0)
    v4f   mqn = *(const v4f*)(matrices + 256 + c0);    // m_{k+1}
    float dtc = delta_t[0];
    float dtn = delta_t[1];

    for (int k = 0; k < NLAYERS - 1; ++k) {
        // Pin x1 registers: forbids remat-as-reload inside the loop.
        asm volatile("" : "+v"(xr[0]), "+v"(xr[1]), "+v"(xr[2]), "+v"(xr[3]));
        asm volatile("" : "+v"(xr[4]), "+v"(xr[5]), "+v"(xr[6]), "+v"(xr[7]));
        asm volatile("" : "+v"(xr[8]), "+v"(xr[9]), "+v"(xr[10]), "+v"(xr[11]));
        asm volatile("" : "+v"(xr[12]), "+v"(xr[13]), "+v"(xr[14]), "+v"(xr[15]));

        // Prefetch m_{k+2}/dt_{k+2}: ~2 layers of cover, no barrier to
        // drain vmcnt -> latency fully hidden.
        const int k2 = (k + 2 < NLAYERS) ? k + 2 : NLAYERS - 1;
        const v4f   mq2   = *(const v4f*)(matrices + k2 * 256 + c0);
        const float dt_nn = delta_t[k2];

        // In-wave stats of z_k.
        const v2f sv = pk_add(s0, s1);
        const v2f qv = pk_add(q0, q1);
        const float S = bcast63(wave_sum64(sv.x + sv.y));
        const float Q = bcast63(wave_sum64(qv.x + qv.y));

        const float dtk  = __builtin_amdgcn_fmed3f(dtc, 0.0f, 6.0f);
        const float mean = S * (1.0f / 4096.0f);
        const float var  = fmaf(-mean, mean, Q * (1.0f / 4096.0f));
        const float rstd = rsqrtf(var + 1e-5f);
        const float g    = gp * rstd;                  // gamma folded
        const float b    = fmaf(-mean, g, bp);         // mean folded
        const float om   = 1.0f - dtk;
        const float gd   = g * dtk;                    // dt folded into clamp
        const float bd   = b * dtk;
        const float hi   = 6.0f * dtk;
        const v2f gd2 = {gd, gd}, bd2 = {bd, bd};
        const v2f om2 = {om, om};
        const v2f omn = {-om, -om};
        const v2f mcA = {mqc.x, mqc.y}, mcB = {mqc.z, mqc.w};
        const v2f mnA = {mqn.x, mqn.y}, mnB = {mqn.z, mqn.w};
        const v2f dmA = pk_fma(omn, mcA, mnA);         // m_{k+1} - om*m_k
        const v2f dmB = pk_fma(omn, mcB, mnB);

        s0 = (v2f){0.f, 0.f}; s1 = (v2f){0.f, 0.f};
        q0 = (v2f){0.f, 0.f}; q1 = (v2f){0.f, 0.f};

        // Fused pass: z' = om*z + dm*x1 + med3(gd*z+bd, 0, hi), + stats.
#pragma unroll
        for (int j = 0; j < 16; ++j) {
            const v2f xA = {xr[j].x, xr[j].y}, xB = {xr[j].z, xr[j].w};
            {
                const int e = 2 * j;
                v2f a = pk_fma(z[e], gd2, bd2);
                a.x = __builtin_amdgcn_fmed3f(a.x, 0.0f, hi);
                a.y = __builtin_amdgcn_fmed3f(a.y, 0.0f, hi);
                v2f u = pk_fma(dmA, xA, a);
                z[e] = pk_fma(om2, z[e], u);
                s0 = pk_add(s0, z[e]);
                q0 = pk_fma(z[e], z[e], q0);
            }
            {
                const int e = 2 * j + 1;
                v2f a = pk_fma(z[e], gd2, bd2);
                a.x = __builtin_amdgcn_fmed3f(a.x, 0.0f, hi);
                a.y = __builtin_amdgcn_fmed3f(a.y, 0.0f, hi);
                v2f u = pk_fma(dmB, xB, a);
                z[e] = pk_fma(om2, z[e], u);
                s1 = pk_add(s1, z[e]);
                q1 = pk_fma(z[e], z[e], q1);
            }
        }

        mqc = mqn; mqn = mq2; dtc = dtn; dtn = dt_nn;
    }

    // Final layer (k = 29): same step with m_30 := 1 -> out = y_30 + x1,
    // coalesced in-place store to ws (T2 relayouts; R16 showed direct
    // scattered stores cost more than T2).
    {
        const v2f sv = pk_add(s0, s1);
        const v2f qv = pk_add(q0, q1);
        const float S = bcast63(wave_sum64(sv.x + sv.y));
        const float Q = bcast63(wave_sum64(qv.x + qv.y));

        const float dtk  = __builtin_amdgcn_fmed3f(dtc, 0.0f, 6.0f);
        const float mean = S * (1.0f / 4096.0f);
        const float var  = fmaf(-mean, mean, Q * (1.0f / 4096.0f));
        const float rstd = rsqrtf(var + 1e-5f);
        const float g    = gp * rstd;
        const float b    = fmaf(-mean, g, bp);
        const float om   = 1.0f - dtk;
        const float gd   = g * dtk;
        const float bd   = b * dtk;
        const float hi   = 6.0f * dtk;
        const v2f gd2 = {gd, gd}, bd2 = {bd, bd};
        const v2f om2 = {om, om};
        const v2f omn = {-om, -om};
        const v2f one2 = {1.0f, 1.0f};
        const v2f mcA = {mqc.x, mqc.y}, mcB = {mqc.z, mqc.w};
        const v2f dmA = pk_fma(omn, mcA, one2);   // 1 - om*m_29
        const v2f dmB = pk_fma(omn, mcB, one2);

#pragma unroll
        for (int j = 0; j < 16; ++j) {
            const v2f xA = {xr[j].x, xr[j].y}, xB = {xr[j].z, xr[j].w};
            v2f o0, o1;
            {
                v2f a = pk_fma(z[2 * j], gd2, bd2);
                a.x = __builtin_amdgcn_fmed3f(a.x, 0.0f, hi);
                a.y = __builtin_amdgcn_fmed3f(a.y, 0.0f, hi);
                v2f u = pk_fma(dmA, xA, a);
                o0 = pk_fma(om2, z[2 * j], u);
            }
            {
                v2f a = pk_fma(z[2 * j + 1], gd2, bd2);
                a.x = __builtin_amdgcn_fmed3f(a.x, 0.0f, hi);
                a.y = __builtin_amdgcn_fmed3f(a.y, 0.0f, hi);
                v2f u = pk_fma(dmB, xB, a);
                o1 = pk_fma(om2, z[2 * j + 1], u);
            }
            v4f o4; o4.x = o0.x; o4.y = o0.y; o4.z = o1.x; o4.w = o1.y;
            *(v4f*)(row + 4 * lane + 256 * j) = o4;
        }
    }
}

// ---------------------------------------------------------------------------
// Fallback (proven 55.6 us, round 0): used only if workspace is too small.
// ---------------------------------------------------------------------------
__global__ __launch_bounds__(TPB) void ode_fused(const float* __restrict__ x,
                                                 const float* __restrict__ delta_t,
                                                 const float* __restrict__ matrices,
                                                 const float* __restrict__ gamma,
                                                 const float* __restrict__ beta,
                                                 float* __restrict__ out) {
    const int bid = blockIdx.x;
    const int p   = ((bid & 7) << 7) | (bid >> 3);
    const int t   = threadIdx.x;

    __shared__ float smat[(NLAYERS + 1) * 256];
    __shared__ float sdt[NLAYERS];
    __shared__ __align__(16) v2f red[2][4];

#pragma unroll
    for (int i = 0; i < NLAYERS; ++i)
        smat[i * 256 + t] = matrices[i * 256 + t];
    if (t < NLAYERS)
        sdt[t] = __builtin_amdgcn_fmed3f(delta_t[t], 0.0f, 6.0f);

    v2f x1[8], y[8];
#pragma unroll
    for (int k = 0; k < 8; ++k) {
        x1[k].x = x[(size_t)(t + 512 * k) * HW + p];
        x1[k].y = x[(size_t)(t + 512 * k + 256) * HW + p];
        y[k] = x1[k];
    }

    const float gp   = gamma[p];
    const float bp   = beta[p];
    const int   wid  = t >> 6;
    const int   lane = t & 63;

    __syncthreads();
    float m_cur = smat[t];

    for (int l = 0; l < NLAYERS; ++l) {
        const float dtl = sdt[l];
        const v2f m2    = {m_cur, m_cur};
        const v2f dt2   = {dtl, dtl};
        const v2f om2   = {1.0f - dtl, 1.0f - dtl};

        v2f z[8];
        v2f sA = {0.f, 0.f}, sB = {0.f, 0.f};
        v2f qA = {0.f, 0.f}, qB = {0.f, 0.f};
#pragma unroll
        for (int k = 0; k < 8; k += 2) {
            z[k]     = __builtin_elementwise_fma(m2, x1[k], y[k]);
            z[k + 1] = __builtin_elementwise_fma(m2, x1[k + 1], y[k + 1]);
            sA += z[k];
            sB += z[k + 1];
            qA = __builtin_elementwise_fma(z[k], z[k], qA);
            qB = __builtin_elementwise_fma(z[k + 1], z[k + 1], qB);
        }
#pragma unroll
        for (int k = 0; k < 8; ++k) y[k] *= om2;

        const v2f sv = sA + sB;
        const v2f qv = qA + qB;
        float s = wave_sum64(sv.x + sv.y);
        float q = wave_sum64(qv.x + qv.y);

        const int par = l & 1;
        if (lane == 63) { v2f w; w.x = s; w.y = q; red[par][wid] = w; }
        m_cur = smat[(l + 1) * 256 + t];
        __syncthreads();

        const float4 r0 = *(const float4*)&red[par][0];
        const float4 r1 = *(const float4*)&red[par][2];
        const float S  = (r0.x + r0.z) + (r1.x + r1.z);
        const float S2 = (r0.y + r0.w) + (r1.y + r1.w);

        const float mean = S * (1.0f / 4096.0f);
        const float var  = fmaf(-mean, mean, S2 * (1.0f / 4096.0f));
        const float rstd = rsqrtf(var + 1e-5f);
        const float g    = gp * rstd;
        const float bb   = fmaf(-mean, g, bp);
        const v2f g2 = {g, g}, b2 = {bb, bb};
        const v2f z0 = {0.f, 0.f}, s6 = {6.f, 6.f};
#pragma unroll
        for (int k = 0; k < 8; ++k) {
            v2f a = __builtin_elementwise_fma(z[k], g2, b2);
            a = __builtin_elementwise_max(a, z0);
            a = __builtin_elementwise_min(a, s6);
            y[k] = __builtin_elementwise_fma(dt2, a, y[k]);
        }
    }

#pragma unroll
    for (int k = 0; k < 8; ++k) {
        out[(size_t)(t + 512 * k) * HW + p]       = y[k].x + x1[k].x;
        out[(size_t)(t + 512 * k + 256) * HW + p] = y[k].y + x1[k].y;
    }
}

extern "C" void kernel_launch(void* const* d_in, const int* in_sizes, int n_in,
                              void* d_out, int out_size, void* d_ws, size_t ws_size,
                              hipStream_t stream) {
    const float* x        = (const float*)d_in[0];   // [16,256,32,32]
    const float* delta_t  = (const float*)d_in[1];   // [30,1]
    const float* matrices = (const float*)d_in[2];   // [30,1,1,16,16]
    const float* gamma    = (const float*)d_in[3];   // [1024]
    const float* beta     = (const float*)d_in[4];   // [1024]
    float* out = (float*)d_out;

    const size_t need = (size_t)HW * NROWS * sizeof(float);   // 16 MiB
    if (d_ws != nullptr && ws_size >= need) {
        float* ws = (float*)d_ws;
        // T1: x [4096,1024] -> ws = x^T [1024,4096]
        txp64<<<dim3(HW / 64, NROWS / 64), dim3(TPB), 0, stream>>>(x, ws, NROWS, HW);
        // Main: 1-wave/channel barrier-free, full-register (waves_per_eu=1).
        ode_zreg<<<dim3(HW), dim3(64), 0, stream>>>(ws, delta_t, matrices, gamma, beta);
        // T2: ws [1024,4096] -> out [4096,1024]
        txp64<<<dim3(NROWS / 64, HW / 64), dim3(TPB), 0, stream>>>(ws, out, HW, NROWS);
    } else {
        ode_fused<<<dim3(HW), dim3(TPB), 0, stream>>>(x, delta_t, matrices, gamma, beta, out);
    }
}